// Round 1
// baseline (1095.991 us; speedup 1.0000x reference)
//
#include <hip/hip_runtime.h>
#include <hip/hip_bf16.h>

// NegSamplerMiniBatch: out[n] = centroids[ idx of 2nd-largest distance(x_n,c_k) ]
// N=262144, D=256, K=256, f32.
//
// Rank key: s_k = |c_k|^2 - 2 x.c_k (monotone in distance). Dot via split-bf16
// MFMA: x = xh + xl, c = ch + cl (truncation splits); dot ~= xh.ch + xl.ch +
// xh.cl, f32 accumulate. Rows with top-3 gap < EPS=0.02 exactly re-ranked in
// f64 by refine_kernel.
//
// This version: C staged via global_load_lds DMA from a global buffer that is
// pre-arranged (in cvt_kernel) in chunk-major MFMA-FRAGMENT order:
//   CHg2[chunk][ctile][l][j]  (l = kslot*16 + (cent&15), j = 0..7)
// so each wave's ds_read_b128 frag fetch is a contiguous, conflict-free 1 KiB
// and the DMA's linear (base + lane*16) LDS write needs no padding/swizzle.
// X is split on the fly and staged in the same fragment order (wave writes are
// a contiguous 1 KiB => conflict-free). Epilogue top-3 is an in-register
// 16-lane shfl_xor butterfly (kills the 32-way-conflicted KEY phase).

typedef __attribute__((ext_vector_type(8))) __bf16 bf16x8;
typedef __attribute__((ext_vector_type(4))) float f32x4;
typedef __attribute__((ext_vector_type(8))) unsigned short u16x8;

#define EPS 0.02f
#define CAP_MAX 65536

__device__ __forceinline__ void split_f32(float v, unsigned short& hi, unsigned short& lo) {
    unsigned u = __float_as_uint(v);
    hi = (unsigned short)(u >> 16);                      // truncate to bf16
    float hif = __uint_as_float(u & 0xFFFF0000u);
    float lov = v - hif;                                 // exact residual
    lo = (unsigned short)(__float_as_uint(lov) >> 16);
}

__device__ __forceinline__ unsigned f32_key(float s) {   // order-preserving u32
    unsigned u = __float_as_uint(s);
    return u ^ ((unsigned)((int)u >> 31) | 0x80000000u);
}
__device__ __forceinline__ float key_to_float(unsigned key) {
    unsigned k = key & 0xFFFFFF00u;
    unsigned u = (k & 0x80000000u) ? (k ^ 0x80000000u) : ~k;
    return __uint_as_float(u);
}

__device__ __forceinline__ void ins3(unsigned& k1, unsigned& k2, unsigned& k3, unsigned v) {
    if (v > k1)      { k3 = k2; k2 = k1; k1 = v; }
    else if (v > k2) { k3 = k2; k2 = v; }
    else if (v > k3) { k3 = v; }
}

__device__ __forceinline__ void gload16(const unsigned short* g, unsigned short* l) {
    __builtin_amdgcn_global_load_lds(
        (const __attribute__((address_space(1))) void*)g,
        (__attribute__((address_space(3))) void*)l, 16, 0, 0);
}

// -------- one-time: C -> bf16 hi/lo in frag-order layout, plus c2 --------
__global__ __launch_bounds__(64) void cvt_kernel(const float* __restrict__ C,
    float* __restrict__ c2f, double* __restrict__ c2d,
    unsigned short* __restrict__ CHg, unsigned short* __restrict__ CLg) {
    const int k = blockIdx.x, l = threadIdx.x;
    float4 v = ((const float4*)(C + (size_t)k * 256))[l];
    unsigned short h0,h1,h2,h3, l0,l1,l2,l3;
    split_f32(v.x,h0,l0); split_f32(v.y,h1,l1); split_f32(v.z,h2,l2); split_f32(v.w,h3,l3);
    // d = 4l .. 4l+3 (same chunk, same kslot, j = d&7 in {0,4})
    const int d = l * 4;
    const size_t off = (size_t)(d >> 5) * 8192          // chunk (16 KB in ushorts)
                     + (size_t)(k >> 4) * 512           // ctile (1 KB)
                     + (size_t)((((d >> 3) & 3) << 4) | (k & 15)) * 8   // lane l'
                     + (d & 7);                         // j
    *(ushort4*)(CHg + off) = make_ushort4(h0,h1,h2,h3);
    *(ushort4*)(CLg + off) = make_ushort4(l0,l1,l2,l3);
    double s = (double)v.x*v.x + (double)v.y*v.y + (double)v.z*v.z + (double)v.w*v.w;
    #pragma unroll
    for (int off2 = 32; off2 >= 1; off2 >>= 1) s += __shfl_xor(s, off2);
    if (l == 0) { c2f[k] = (float)s; c2d[k] = s; }
}

// -------- fused split-bf16 MFMA GEMM + butterfly top-3 + gather-write --------
__global__ __launch_bounds__(256, 3) void score_kernel(
    const float* __restrict__ X, const unsigned short* __restrict__ CHg,
    const unsigned short* __restrict__ CLg, const float* __restrict__ C,
    const float* __restrict__ c2f, unsigned* __restrict__ counter,
    unsigned* __restrict__ list, unsigned cap, float* __restrict__ out) {

    // LDS (ushort units): XH2[4 tiles][512] XL2[4][512] CH2[16][512] CL2[16][512]
    // = 20480 ushorts = 40 KB. Each tile is one MFMA operand set in frag order:
    // tile[l*8 + j] = elem(row/col = tile*16 + (l&15), k = (l>>4)*8 + j).
    __shared__ __align__(16) unsigned short SH[20480];
    __shared__ float c2s[256];
    __shared__ int bestIdx[64];

    unsigned short* XH2 = SH;           // 2048
    unsigned short* XL2 = SH + 2048;    // 2048
    unsigned short* CH2 = SH + 4096;    // 8192
    unsigned short* CL2 = SH + 12288;   // 8192

    const int t = threadIdx.x;
    const int rowBase = blockIdx.x * 64;
    c2s[t] = c2f[t];

    const int lane = t & 63, w = t >> 6;
    const int lane16 = t & 15, quad = (t >> 4) & 3;

    f32x4 acc[4][4];
    #pragma unroll
    for (int r = 0; r < 4; ++r)
        #pragma unroll
        for (int c = 0; c < 4; ++c) acc[r][c] = (f32x4)0.f;

    // X staging role: row xr, k-slot xs; write lands at frag position
    // l' = xs*16 + (xr&15) of tile xr>>4  => per-wave writes cover a
    // contiguous 1 KiB (t&3 varies fastest) => conflict-free.
    const int xr = t >> 2, xs = t & 3;
    const float* xbase = X + (size_t)(rowBase + xr) * 256 + xs * 8;
    const int xoff = (xr >> 4) * 512 + ((xs << 4) | (xr & 15)) * 8;

    float4 xa = ((const float4*)xbase)[0];
    float4 xb = ((const float4*)xbase)[1];

    for (int chunk = 0; chunk < 8; ++chunk) {
        union { u16x8 v; unsigned short s[8]; } hu, lu;
        {
            float xv[8] = {xa.x, xa.y, xa.z, xa.w, xb.x, xb.y, xb.z, xb.w};
            #pragma unroll
            for (int q = 0; q < 8; ++q) split_f32(xv[q], hu.s[q], lu.s[q]);
        }

        __syncthreads();   // previous chunk's frags consumed

        // C DMA: wave w pulls ctiles w*4..w*4+3 (hi+lo), 1 KiB per instr,
        // global layout == LDS layout (linear, base + lane*16).
        {
            const size_t gb = (size_t)chunk * 8192 + (size_t)(w * 4) * 512 + (size_t)lane * 8;
            const int lb = (w * 4) * 512 + lane * 8;
            #pragma unroll
            for (int s2 = 0; s2 < 4; ++s2) {
                gload16(CHg + gb + s2 * 512, CH2 + lb + s2 * 512);
                gload16(CLg + gb + s2 * 512, CL2 + lb + s2 * 512);
            }
        }
        *(u16x8*)(XH2 + xoff) = hu.v;
        *(u16x8*)(XL2 + xoff) = lu.v;
        __syncthreads();   // implicit vmcnt(0)+lgkmcnt(0): DMA + writes visible

        // prefetch next chunk's X under the MFMA cluster
        if (chunk < 7) {
            const float* nx = xbase + (chunk + 1) * 32;
            xa = ((const float4*)nx)[0];
            xb = ((const float4*)nx)[1];
        }

        // frag reads: contiguous 1 KiB per wave per tile => conflict-free
        bf16x8 ah[4], al[4];
        #pragma unroll
        for (int r = 0; r < 4; ++r) {
            ah[r] = *(const bf16x8*)(XH2 + r * 512 + lane * 8);
            al[r] = *(const bf16x8*)(XL2 + r * 512 + lane * 8);
        }
        #pragma unroll
        for (int c = 0; c < 4; ++c) {
            const int cb = (w * 4 + c) * 512 + lane * 8;
            bf16x8 bh = *(const bf16x8*)(CH2 + cb);
            bf16x8 bl = *(const bf16x8*)(CL2 + cb);
            #pragma unroll
            for (int r = 0; r < 4; ++r) {
                acc[r][c] = __builtin_amdgcn_mfma_f32_16x16x32_bf16(ah[r], bh, acc[r][c], 0, 0, 0);
                acc[r][c] = __builtin_amdgcn_mfma_f32_16x16x32_bf16(al[r], bh, acc[r][c], 0, 0, 0);
                acc[r][c] = __builtin_amdgcn_mfma_f32_16x16x32_bf16(ah[r], bl, acc[r][c], 0, 0, 0);
            }
        }
    }
    __syncthreads();   // stage dead; overlay WKEY

    // WKEY[row][13]: per-row, per-wave top-3 (stride 13 dwords: coprime to 32)
    unsigned* WKEY = (unsigned*)SH;   // 64*13*4 = 3328 B

    float cc2[4];
    #pragma unroll
    for (int c = 0; c < 4; ++c) cc2[c] = c2s[w * 64 + c * 16 + lane16];

    #pragma unroll
    for (int r = 0; r < 4; ++r) {
        #pragma unroll
        for (int i = 0; i < 4; ++i) {
            unsigned k1 = 0, k2 = 0, k3 = 0;   // all real keys > 0
            #pragma unroll
            for (int c = 0; c < 4; ++c) {
                float s = cc2[c] - 2.f * acc[r][c][i];
                unsigned cent = (unsigned)(w * 64 + c * 16 + lane16);
                unsigned key = (f32_key(s) & 0xFFFFFF00u) | (255u - cent);
                ins3(k1, k2, k3, key);
            }
            // butterfly over the 16-lane group (masks < 16 stay in-quad);
            // partners hold disjoint column sets at every step
            #pragma unroll
            for (int m = 1; m <= 8; m <<= 1) {
                unsigned o1 = __shfl_xor(k1, m);
                unsigned o2 = __shfl_xor(k2, m);
                unsigned o3 = __shfl_xor(k3, m);
                ins3(k1, k2, k3, o1); ins3(k1, k2, k3, o2); ins3(k1, k2, k3, o3);
            }
            if (lane16 == 0) {
                const int row = r * 16 + quad * 4 + i;
                unsigned* p = WKEY + row * 13 + w * 3;
                p[0] = k1; p[1] = k2; p[2] = k3;
            }
        }
    }
    __syncthreads();

    // final: one thread per row merges 4 waves' triples (stride-13 => no conflict)
    if (t < 64) {
        unsigned k1 = 0, k2 = 0, k3 = 0;
        #pragma unroll
        for (int w2 = 0; w2 < 4; ++w2) {
            const unsigned* p = WKEY + t * 13 + w2 * 3;
            ins3(k1, k2, k3, p[0]); ins3(k1, k2, k3, p[1]); ins3(k1, k2, k3, p[2]);
        }
        bestIdx[t] = 255 - (int)(k2 & 0xFFu);
        float s1 = key_to_float(k1), s2 = key_to_float(k2), s3 = key_to_float(k3);
        if (s1 - s2 < EPS || s2 - s3 < EPS) {
            unsigned p = atomicAdd(counter, 1u);
            if (p < cap) list[p] = (unsigned)(rowBase + t);
        }
    }
    __syncthreads();

    // gather-write: 4 threads per row, 16 float4 each
    {
        const int r = t >> 2, q0 = t & 3;
        const int c = bestIdx[r];
        const float4* src = (const float4*)(C + (size_t)c * 256);
        float4* dst = (float4*)(out + (size_t)(rowBase + r) * 256);
        #pragma unroll
        for (int q = 0; q < 16; ++q) dst[q0 + 4 * q] = src[q0 + 4 * q];
    }
}

// -------- exact f64 re-rank of flagged rows --------
__global__ __launch_bounds__(256) void refine_kernel(
    const float* __restrict__ X, const float* __restrict__ C,
    const double* __restrict__ c2d, const unsigned* __restrict__ counter,
    const unsigned* __restrict__ list, unsigned cap, float* __restrict__ out) {

    __shared__ float xs[256];
    __shared__ double sh[256];
    __shared__ int b2s;
    unsigned count = *counter;
    if (count > cap) count = cap;
    const int k = threadIdx.x;

    for (unsigned idx = blockIdx.x; idx < count; idx += gridDim.x) {
        const unsigned row = list[idx];
        xs[k] = X[(size_t)row * 256 + k];
        __syncthreads();
        const float4* cp = (const float4*)(C + (size_t)k * 256);
        double a = 0.0;
        #pragma unroll 4
        for (int j = 0; j < 64; ++j) {
            float4 c4 = cp[j];
            a += (double)c4.x * xs[4 * j + 0] + (double)c4.y * xs[4 * j + 1]
               + (double)c4.z * xs[4 * j + 2] + (double)c4.w * xs[4 * j + 3];
        }
        sh[k] = c2d[k] - 2.0 * a;
        __syncthreads();
        if (k == 0) {
            double b1 = -1e300, b2 = -1e300;
            int i1 = 0, i2 = 0;
            for (int q = 0; q < 256; ++q) {
                double s = sh[q];
                if (s > b1)      { b2 = b1; i2 = i1; b1 = s; i1 = q; }
                else if (s > b2) { b2 = s;  i2 = q; }
            }
            b2s = i2;
        }
        __syncthreads();
        const int csel = b2s;
        if (k < 64) {
            const float4* src = (const float4*)(C + (size_t)csel * 256);
            float4* dst = (float4*)(out + (size_t)row * 256);
            dst[k] = src[k];
        }
        __syncthreads();   // xs/sh reused next iteration
    }
}

extern "C" void kernel_launch(void* const* d_in, const int* in_sizes, int n_in,
                              void* d_out, int out_size, void* d_ws, size_t ws_size,
                              hipStream_t stream) {
    const float* X = (const float*)d_in[0];
    const float* C = (const float*)d_in[1];
    float* out = (float*)d_out;
    const int N = in_sizes[0] / 256;

    // ws: [0,64) counter | [64) c2f(1KB) | [2048) c2d(2KB) | [4096) CH(128KB)
    //     | [135168) CL(128KB) | [266240) flag list
    unsigned* counter = (unsigned*)d_ws;
    float* c2f = (float*)((char*)d_ws + 64);
    double* c2d = (double*)((char*)d_ws + 2048);
    unsigned short* CHg = (unsigned short*)((char*)d_ws + 4096);
    unsigned short* CLg = (unsigned short*)((char*)d_ws + 135168);
    unsigned* list = (unsigned*)((char*)d_ws + 266240);
    unsigned cap = 0;
    if (ws_size > 266240) {
        size_t c = (ws_size - 266240) / 4;
        cap = (unsigned)(c < (size_t)CAP_MAX ? c : (size_t)CAP_MAX);
    }

    hipMemsetAsync(d_ws, 0, 64, stream);
    cvt_kernel<<<256, 64, 0, stream>>>(C, c2f, c2d, CHg, CLg);
    score_kernel<<<N / 64, 256, 0, stream>>>(X, CHg, CLg, C, c2f, counter, list, cap, out);
    refine_kernel<<<1024, 256, 0, stream>>>(X, C, c2d, counter, list, cap, out);
}